// Round 4
// baseline (84.514 us; speedup 1.0000x reference)
//
#include <hip/hip_runtime.h>

// CP-rank-32 tensor reconstruction: out[i,j,k] = sum_r W0[i,r]*W1[j,r]*W2[k,r]
// out 256x256x1024 fp32 (268 MB). Write floor ~40us (fill kernel measures 6.9 TB/s).
// R3: 83.5us with LDS-c + per-block W2T re-read (1 GB L2) + 4 waves/SIMD.
// R4: W2T k-column set held in registers (32 float4, loaded once per thread),
//     C[i,j,r]=W0*W1 precomputed to ws (8 MB), inner loop = pure FMA + 1 NT store.
// FMA order per output element: r=0..31 sequential fused — bit-exact vs R3 (absmax 0.0).

constexpr int I_DIM = 256;
constexpr int J_DIM = 256;
constexpr int K_DIM = 1024;
constexpr int RNK   = 32;
constexpr int JSEG  = 64;   // j's per block in the register-resident path

typedef float f32x4 __attribute__((ext_vector_type(4)));

__device__ __forceinline__ void fma4(float4& a, float s, const float4& v) {
    a.x = fmaf(s, v.x, a.x);
    a.y = fmaf(s, v.y, a.y);
    a.z = fmaf(s, v.z, a.z);
    a.w = fmaf(s, v.w, a.w);
}

__device__ __forceinline__ void store_nt4(float* p, const float4& v) {
    f32x4 t = { v.x, v.y, v.z, v.w };
    __builtin_nontemporal_store(t, reinterpret_cast<f32x4*>(p));
}

// W2 (1024x32, row-major) -> W2T (32x1024): main-loop loads coalesced in k.
__global__ void transpose_w2(const float* __restrict__ W2, float* __restrict__ W2T) {
    int idx = blockIdx.x * 256 + threadIdx.x;   // 0 .. 32767
    int r = idx >> 10;
    int k = idx & (K_DIM - 1);
    W2T[r * K_DIM + k] = W2[k * RNK + r];
}

// C[i][j][r] = W0[i,r] * W1[j,r]   (256*256*32 floats = 8 MB)
__global__ void precompute_c(const float* __restrict__ W0, const float* __restrict__ W1,
                             float* __restrict__ C) {
    int idx = blockIdx.x * 256 + threadIdx.x;   // 0 .. 2097151
    int r = idx & 31;
    int j = (idx >> 5) & 255;
    int i = idx >> 13;
    C[idx] = W0[i * RNK + r] * W1[j * RNK + r];
}

// Block: one i, JSEG j's, all k (thread = one k-float4). W2T columns in registers.
__global__ __launch_bounds__(256, 2) void cp_recon_reg(const float* __restrict__ C,
                                                       const float* __restrict__ W2T,
                                                       float* __restrict__ out) {
    const int i     = blockIdx.x >> 2;            // / (J_DIM/JSEG)
    const int jbase = (blockIdx.x & 3) * JSEG;
    const int k     = threadIdx.x * 4;

    // Whole rank-32 slice for this thread's 4 k's: 32 float4 = 128 VGPRs, loaded once.
    float4 w[RNK];
#pragma unroll
    for (int r = 0; r < RNK; ++r)
        w[r] = *reinterpret_cast<const float4*>(&W2T[r * K_DIM + k]);

    const float* __restrict__ crow = C + (size_t)(i * J_DIM + jbase) * RNK;
    float* __restrict__ orow = out + (size_t)(i * J_DIM + jbase) * K_DIM + k;

#pragma unroll 1
    for (int jj = 0; jj < JSEG; ++jj) {
        // Wave-uniform address: 32 floats, L2-resident (8 MB C), scalar-izable.
        float cr[RNK];
#pragma unroll
        for (int r = 0; r < RNK; ++r) cr[r] = crow[jj * RNK + r];

        float4 acc = make_float4(0.f, 0.f, 0.f, 0.f);
#pragma unroll
        for (int r = 0; r < RNK; ++r) fma4(acc, cr[r], w[r]);

        store_nt4(orow + (size_t)jj * K_DIM, acc);
    }
}

// ---- Fallback (ws too small for C): R3's working LDS-c kernel (83.5us) ----
constexpr int JT = 8;
__global__ __launch_bounds__(256, 4) void cp_recon_t(const float* __restrict__ W0,
                                                     const float* __restrict__ W1,
                                                     const float* __restrict__ W2T,
                                                     float* __restrict__ out) {
    __shared__ __align__(16) float c[JT][RNK];
    const int i     = blockIdx.x >> 5;
    const int jbase = (blockIdx.x & 31) * JT;
    const int tid   = threadIdx.x;

    if (tid < JT * RNK) {
        int jj = tid >> 5;
        int r  = tid & 31;
        c[jj][r] = W0[i * RNK + r] * W1[(jbase + jj) * RNK + r];
    }
    __syncthreads();

    const int k = tid * 4;
    float4 acc[JT];
#pragma unroll
    for (int jj = 0; jj < JT; ++jj) acc[jj] = make_float4(0.f, 0.f, 0.f, 0.f);

#pragma unroll 2
    for (int rc = 0; rc < RNK; rc += 4) {
        float4 wv[4];
#pragma unroll
        for (int q = 0; q < 4; ++q)
            wv[q] = *reinterpret_cast<const float4*>(&W2T[(rc + q) * K_DIM + k]);
#pragma unroll
        for (int jj = 0; jj < JT; ++jj) {
            float4 c4 = *reinterpret_cast<const float4*>(&c[jj][rc]);
            fma4(acc[jj], c4.x, wv[0]);
            fma4(acc[jj], c4.y, wv[1]);
            fma4(acc[jj], c4.z, wv[2]);
            fma4(acc[jj], c4.w, wv[3]);
        }
    }
#pragma unroll
    for (int jj = 0; jj < JT; ++jj) {
        int o = (i * J_DIM + jbase + jj) * K_DIM + k;
        store_nt4(&out[o], acc[jj]);
    }
}

// ---- Fallback (no ws at all): direct W2 reads ----
__global__ __launch_bounds__(256, 4) void cp_recon_d(const float* __restrict__ W0,
                                                     const float* __restrict__ W1,
                                                     const float* __restrict__ W2,
                                                     float* __restrict__ out) {
    __shared__ __align__(16) float c[JT][RNK];
    const int i     = blockIdx.x >> 5;
    const int jbase = (blockIdx.x & 31) * JT;
    const int tid   = threadIdx.x;

    if (tid < JT * RNK) {
        int jj = tid >> 5;
        int r  = tid & 31;
        c[jj][r] = W0[i * RNK + r] * W1[(jbase + jj) * RNK + r];
    }
    __syncthreads();

    const int k = tid * 4;
    float4 acc[JT];
#pragma unroll
    for (int jj = 0; jj < JT; ++jj) acc[jj] = make_float4(0.f, 0.f, 0.f, 0.f);

    for (int rc = 0; rc < RNK; rc += 4) {
        float4 row[4];
#pragma unroll
        for (int q = 0; q < 4; ++q)
            row[q] = *reinterpret_cast<const float4*>(&W2[(k + q) * RNK + rc]);
#pragma unroll
        for (int jj = 0; jj < JT; ++jj) {
            float4 c4 = *reinterpret_cast<const float4*>(&c[jj][rc]);
            acc[jj].x = fmaf(c4.x, row[0].x, fmaf(c4.y, row[0].y, fmaf(c4.z, row[0].z, fmaf(c4.w, row[0].w, acc[jj].x))));
            acc[jj].y = fmaf(c4.x, row[1].x, fmaf(c4.y, row[1].y, fmaf(c4.z, row[1].z, fmaf(c4.w, row[1].w, acc[jj].y))));
            acc[jj].z = fmaf(c4.x, row[2].x, fmaf(c4.y, row[2].y, fmaf(c4.z, row[2].z, fmaf(c4.w, row[2].w, acc[jj].z))));
            acc[jj].w = fmaf(c4.x, row[3].x, fmaf(c4.y, row[3].y, fmaf(c4.z, row[3].z, fmaf(c4.w, row[3].w, acc[jj].w))));
        }
    }
#pragma unroll
    for (int jj = 0; jj < JT; ++jj) {
        int o = (i * J_DIM + jbase + jj) * K_DIM + k;
        store_nt4(&out[o], acc[jj]);
    }
}

extern "C" void kernel_launch(void* const* d_in, const int* in_sizes, int n_in,
                              void* d_out, int out_size, void* d_ws, size_t ws_size,
                              hipStream_t stream) {
    const float* W0 = (const float*)d_in[0];
    const float* W1 = (const float*)d_in[1];
    const float* W2 = (const float*)d_in[2];
    float* out = (float*)d_out;

    const size_t w2t_bytes = (size_t)RNK * K_DIM * sizeof(float);          // 128 KB
    const size_t c_bytes   = (size_t)I_DIM * J_DIM * RNK * sizeof(float);  // 8 MB

    if (ws_size >= w2t_bytes + c_bytes) {
        float* W2T = (float*)d_ws;
        float* Cbuf = (float*)((char*)d_ws + w2t_bytes);
        transpose_w2<<<(RNK * K_DIM) / 256, 256, 0, stream>>>(W2, W2T);
        precompute_c<<<(I_DIM * J_DIM * RNK) / 256, 256, 0, stream>>>(W0, W1, Cbuf);
        cp_recon_reg<<<I_DIM * (J_DIM / JSEG), 256, 0, stream>>>(Cbuf, W2T, out);
    } else if (ws_size >= w2t_bytes) {
        float* W2T = (float*)d_ws;
        transpose_w2<<<(RNK * K_DIM) / 256, 256, 0, stream>>>(W2, W2T);
        cp_recon_t<<<I_DIM * (J_DIM / JT), 256, 0, stream>>>(W0, W1, W2T, out);
    } else {
        cp_recon_d<<<I_DIM * (J_DIM / JT), 256, 0, stream>>>(W0, W1, W2, out);
    }
}